// Round 11
// baseline (719.549 us; speedup 1.0000x reference)
//
#include <hip/hip_runtime.h>
#include <math.h>

#define BATCH 4
#define NN 4096
#define DIN 128
#define DE 64
#define KK 16

#define GMAXF 2.9135f   // rigorous upper bound on f32 G = log(-log(q+1e-8))
#define SCRMARG 1e-3f   // logf-screen margin (r7-verified)

// ---------------- K1: xe = x @ W + bias (r7-verified golden replica) ----------------
__global__ __launch_bounds__(256) void embed_kernel(
    const float* __restrict__ x, const float* __restrict__ W,
    const float* __restrict__ bias, float* __restrict__ xe) {
#pragma clang fp contract(off)
  __shared__ float wl[DIN][DE];
  __shared__ float xs[4][DIN];
  int t = threadIdx.x;
  for (int i = t * 4; i < DIN * DE; i += 1024)
    *(float4*)&wl[i >> 6][i & 63] = *(const float4*)&W[i];
  {
    int rr = t >> 6, dd = (t & 63) * 2;
    const float* src = x + ((size_t)blockIdx.x * 4 + rr) * DIN + dd;
    xs[rr][dd] = src[0];
    xs[rr][dd + 1] = src[1];
  }
  __syncthreads();
  int w = t >> 6, lane = t & 63;
  float acc = 0.f;
#pragma unroll
  for (int d = 0; d < DIN; ++d)
    acc = __builtin_fmaf(xs[w][d], wl[d][lane], acc);  // sequential FMA chain
  xe[((size_t)blockIdx.x * 4 + w) * DE + lane] = acc + bias[lane];
}

// numpy pairwise sum (n=64, scalar 8-accumulator path) of squares (r7-verified)
static __device__ __forceinline__ float np_pairwise_sq64(const float* a) {
#pragma clang fp contract(off)
  float p[8];
#pragma unroll
  for (int j = 0; j < 8; ++j) { float v = a[j]; p[j] = v * v; }
#pragma unroll
  for (int i = 8; i < 64; i += 8)
#pragma unroll
    for (int j = 0; j < 8; ++j) { float v = a[i + j]; p[j] = p[j] + v * v; }
  return ((p[0] + p[1]) + (p[2] + p[3])) + ((p[4] + p[5]) + (p[6] + p[7]));
}

// ---------------- K2: squared norms ----------------
__global__ __launch_bounds__(256) void sqnorm_kernel(
    const float* __restrict__ xe, float* __restrict__ sq) {
  int row = blockIdx.x * 256 + threadIdx.x;
  sq[row] = np_pairwise_sq64(xe + (size_t)row * DE);
}

// ---------------- K3: fused segmented top-16, block-uniform column base ----------------
// Thread = (row, seg). Column tile / sqc addresses derive from blockIdx ONLY ->
// scalarized (s_load + FMA-from-SGPR). __launch_bounds__(256,2): 256-VGPR budget
// so rowv[16] (64 VGPRs) stays register-resident — r10's 76-VGPR cap spilled it
// to scratch (24.7 MB WRITE_SIZE), which was the bottleneck.
template <int SEGS>
__global__ __launch_bounds__(256, 2) void topk_seg_kernel(
    const float* __restrict__ xe, const float* __restrict__ sq,
    const float* __restrict__ q, const float* __restrict__ temp,
    float* __restrict__ Bv, unsigned short* __restrict__ Bc) {
#pragma clang fp contract(off)
  const int SEGW = NN / SEGS;
  int rg = (int)blockIdx.x / SEGS;
  int sg = (int)blockIdx.x % SEGS;
  // block-uniform batch + row-group base (256 | 4096 => never crosses batch)
  int bu = (rg * 256) >> 12;
  int n0 = (rg * 256) & (NN - 1);
  int n = n0 + (int)threadIdx.x;            // per-lane row within batch
  int row = (bu << 12) + n;                 // per-lane global row
  const float* xb = xe + (size_t)bu * NN * DE;   // UNIFORM
  const float* sqb = sq + ((size_t)bu << 12);    // UNIFORM

  float4 rowv[16];
  const float* rp = xb + (size_t)n * DE;
#pragma unroll
  for (int i = 0; i < 16; ++i) rowv[i] = ((const float4*)rp)[i];
  float sqr = sqb[n];

  double tc = (double)temp[0];
  float s32 = (float)exp(fmin(fmax(tc, -5.0), 5.0));
  const float* qrow = q + ((size_t)bu * NN + n) * NN;

  float topv[16];
  int topi[16];
#pragma unroll
  for (int k = 0; k < 16; ++k) { topv[k] = __builtin_inff(); topi[k] = 0; }

  int base = sg * SEGW;  // uniform
  for (int cg = base; cg < base + SEGW; cg += 8) {
    // uniform sqc loads
    float4 s0 = *(const float4*)(sqb + cg);
    float4 s1 = *(const float4*)(sqb + cg + 4);
    float sqc8[8] = {s0.x, s0.y, s0.z, s0.w, s1.x, s1.y, s1.z, s1.w};

    // gram: sequential FMA d=0..63 (golden order); column operands uniform
    const float* cb = xb + (size_t)cg * DE;  // UNIFORM
    float acc[8] = {0, 0, 0, 0, 0, 0, 0, 0};
#pragma unroll
    for (int dq = 0; dq < 16; ++dq) {
      float4 rv = rowv[dq];
#pragma unroll
      for (int c = 0; c < 8; ++c) {
        float4 bv = *(const float4*)(cb + (size_t)c * DE + dq * 4);  // uniform
        float a = acc[c];
        a = __builtin_fmaf(rv.x, bv.x, a);
        a = __builtin_fmaf(rv.y, bv.y, a);
        a = __builtin_fmaf(rv.z, bv.z, a);
        a = __builtin_fmaf(rv.w, bv.w, a);
        acc[c] = a;
      }
    }
    float P[8];
#pragma unroll
    for (int c = 0; c < 8; ++c) {
      float u = (sqr + sqc8[c]) - 2.0f * acc[c];
      float D = fmaxf(u, 0.0f);
      P[c] = D * s32;
    }

    float at15 = topv[15];
    unsigned m = 0;
#pragma unroll
    for (int c = 0; c < 8; ++c)
      m |= (unsigned)((P[c] - GMAXF) < at15) << c;  // sound prescreen

    float p0 = P[0], p1 = P[1], p2 = P[2], p3 = P[3];
    float p4 = P[4], p5 = P[5], p6 = P[6], p7 = P[7];
    while (m) {
      int c = __builtin_ctz(m);
      m &= m - 1;
      float a0 = (c & 1) ? p1 : p0, a1 = (c & 1) ? p3 : p2;
      float a2 = (c & 1) ? p5 : p4, a3 = (c & 1) ? p7 : p6;
      float b0 = (c & 2) ? a1 : a0, b1 = (c & 2) ? a3 : a2;
      float Ps = (c & 4) ? b1 : b0;
      float qv = qrow[cg + c];
      float t1 = qv + 1e-8f;
      // cheap screen (device logf, err ~1e-5 << 1e-3 margin; r7-verified)
      float lq_scr = Ps - logf(-logf(t1));
      if (lq_scr < at15 + SCRMARG) {
        float l1 = (float)log((double)t1);  // correctly-rounded f32 log
        float G = (float)log((double)(-l1));
        float lq = Ps - G;
        if (lq < topv[15]) {
          int col = cg + c;
#pragma unroll
          for (int k = 15; k >= 1; --k) {
            bool ltk = lq < topv[k];
            bool ltk1 = lq < topv[k - 1];
            topv[k] = ltk ? (ltk1 ? topv[k - 1] : lq) : topv[k];
            topi[k] = ltk ? (ltk1 ? topi[k - 1] : col) : topi[k];
          }
          if (lq < topv[0]) { topv[0] = lq; topi[0] = col; }
          at15 = topv[15];
        }
      }
    }
  }
  float* dv = Bv + ((size_t)row * SEGS + sg) * 16;
  unsigned short* dc = Bc + ((size_t)row * SEGS + sg) * 16;
#pragma unroll
  for (int k = 0; k < 16; ++k) {
    dv[k] = topv[k];
    dc[k] = (unsigned short)topi[k];
  }
}

// ---------------- K4: merge per-seg lists -> outputs ----------------
template <int SEGS>
__global__ __launch_bounds__(256) void mergeB_kernel(
    const float* __restrict__ Bv, const unsigned short* __restrict__ Bc,
    float* __restrict__ e0, float* __restrict__ e1, float* __restrict__ lp) {
  int row = (int)blockIdx.x * 256 + (int)threadIdx.x;
  int b = row >> 12;
  int n = row & (NN - 1);
  const float* vb = Bv + (size_t)row * SEGS * 16;
  const unsigned short* cbp = Bc + (size_t)row * SEGS * 16;
  float hv[SEGS];
  int hc[SEGS];
  int hi[SEGS];
#pragma unroll
  for (int s = 0; s < SEGS; ++s) {
    hv[s] = vb[(size_t)s * 16];
    hc[s] = cbp[(size_t)s * 16];
    hi[s] = 0;
  }
  size_t o = (size_t)row * KK;
#pragma unroll
  for (int k = 0; k < KK; ++k) {
    float best = __builtin_inff();
    int bs = 0;
#pragma unroll
    for (int s = 0; s < SEGS; ++s)
      if (hv[s] < best) { best = hv[s]; bs = s; }  // strict <: lowest seg on ties
    int bcol = 0;
#pragma unroll
    for (int s = 0; s < SEGS; ++s)
      if (bs == s) bcol = hc[s];
    lp[o + k] = -best;
    e0[o + k] = (float)(bcol + b * NN);
    e1[o + k] = (float)(n + b * NN);
#pragma unroll
    for (int s = 0; s < SEGS; ++s)
      if (bs == s) {
        hi[s]++;
        bool ok = hi[s] < 16;
        hv[s] = ok ? vb[(size_t)s * 16 + hi[s]] : __builtin_inff();
        hc[s] = ok ? (int)cbp[(size_t)s * 16 + hi[s]] : 0;
      }
  }
}

extern "C" void kernel_launch(void* const* d_in, const int* in_sizes, int n_in,
                              void* d_out, int out_size, void* d_ws,
                              size_t ws_size, hipStream_t stream) {
  (void)in_sizes; (void)n_in; (void)out_size;
  const float* x = (const float*)d_in[0];
  // d_in[1] = A (unused placeholder)
  const float* W = (const float*)d_in[2];
  const float* bias = (const float*)d_in[3];
  const float* temp = (const float*)d_in[4];
  const float* q = (const float*)d_in[5];

  float* xe = (float*)d_out;                 // [4,4096,64]
  float* e0 = xe + (size_t)BATCH * NN * DE;  // edges row 0 (indices)
  float* e1 = e0 + (size_t)BATCH * NN * KK;  // edges row 1 (rows)
  float* lp = e1 + (size_t)BATCH * NN * KK;  // logprobs

  const int ROWS = BATCH * NN;  // 16384
  char* ws = (char*)d_ws;
  float* sq = (float*)ws;  // 64 KB
  char* buf = ws + 65536;
  // need(S) = 64K + S*ROWS*(16*4 + 16*2)
  auto need = [&](size_t s) { return (size_t)65536 + s * (size_t)ROWS * 96; };
  int segs = (ws_size >= need(16)) ? 16 : (ws_size >= need(8)) ? 8 : 4;

  embed_kernel<<<BATCH * NN / 4, 256, 0, stream>>>(x, W, bias, xe);
  sqnorm_kernel<<<ROWS / 256, 256, 0, stream>>>(xe, sq);

#define RUN(S)                                                                \
  {                                                                           \
    float* Bv = (float*)buf;                                                  \
    unsigned short* Bc = (unsigned short*)(buf + (size_t)S * ROWS * 64);      \
    topk_seg_kernel<S><<<(ROWS / 256) * S, 256, 0, stream>>>(xe, sq, q, temp, \
                                                             Bv, Bc);         \
    mergeB_kernel<S><<<ROWS / 256, 256, 0, stream>>>(Bv, Bc, e0, e1, lp);     \
  }
  if (segs == 16) RUN(16)
  else if (segs == 8) RUN(8)
  else RUN(4)
#undef RUN
}

// Round 12
// 394.806 us; speedup vs baseline: 1.8225x; 1.8225x over previous
//
#include <hip/hip_runtime.h>
#include <math.h>

#define BATCH 4
#define NN 4096
#define DIN 128
#define DE 64
#define KK 16
#define CAP 128        // candidate slots per row (expected ~25-40 survivors)
#define GMAXF 2.9135f  // rigorous upper bound on f32 G = log(-log(q+1e-8))
#define GMINPAD 16.65f // rigorous: G > -16.64 => lq_i < P_i + 16.64
#define SCRMARG 0.01f  // f32 rounding slack on the screen compare

// ---------------- K1: xe = x @ W + bias (r7-verified golden replica) ----------------
__global__ __launch_bounds__(256) void embed_kernel(
    const float* __restrict__ x, const float* __restrict__ W,
    const float* __restrict__ bias, float* __restrict__ xe) {
#pragma clang fp contract(off)
  __shared__ float wl[DIN][DE];
  __shared__ float xs[4][DIN];
  int t = threadIdx.x;
  for (int i = t * 4; i < DIN * DE; i += 1024)
    *(float4*)&wl[i >> 6][i & 63] = *(const float4*)&W[i];
  {
    int rr = t >> 6, dd = (t & 63) * 2;
    const float* src = x + ((size_t)blockIdx.x * 4 + rr) * DIN + dd;
    xs[rr][dd] = src[0];
    xs[rr][dd + 1] = src[1];
  }
  __syncthreads();
  int w = t >> 6, lane = t & 63;
  float acc = 0.f;
#pragma unroll
  for (int d = 0; d < DIN; ++d)
    acc = __builtin_fmaf(xs[w][d], wl[d][lane], acc);  // sequential FMA chain
  xe[((size_t)blockIdx.x * 4 + w) * DE + lane] = acc + bias[lane];
}

// numpy pairwise sum (n=64, scalar 8-accumulator path) of squares (r7-verified)
static __device__ __forceinline__ float np_pairwise_sq64(const float* a) {
#pragma clang fp contract(off)
  float p[8];
#pragma unroll
  for (int j = 0; j < 8; ++j) { float v = a[j]; p[j] = v * v; }
#pragma unroll
  for (int i = 8; i < 64; i += 8)
#pragma unroll
    for (int j = 0; j < 8; ++j) { float v = a[i + j]; p[j] = p[j] + v * v; }
  return ((p[0] + p[1]) + (p[2] + p[3])) + ((p[4] + p[5]) + (p[6] + p[7]));
}

// ---------------- K2: squared norms ----------------
__global__ __launch_bounds__(256) void sqnorm_kernel(
    const float* __restrict__ xe, float* __restrict__ sq) {
  int row = blockIdx.x * 256 + threadIdx.x;
  sq[row] = np_pairwise_sq64(xe + (size_t)row * DE);
}

// ---------------- K3/K5: 2D register-blocked GEMM pass ----------------
// Block = 128 rows x 1024 cols (8 subtiles of 128). Thread (tx,ty) owns 8x8.
// LDS: At[d][r], Bt[d][c] (transposed) -> per d: 4x ds_read_b128 + 64 FMA.
// P math op-identical to r7 chain. PASSA: per-(row,tx,colseg) min2 -> cellmin.
// PASSB: screen P-GMAXF < thrP, append (P,col) to per-row candidate buffer.
template <bool PASSB>
__global__ __launch_bounds__(256, 2) void gemm_pass_kernel(
    const float* __restrict__ xe, const float* __restrict__ sq,
    const float* __restrict__ temp, float2* __restrict__ cellmin,
    const float* __restrict__ thrP, int* __restrict__ cnt,
    uint2* __restrict__ cand) {
#pragma clang fp contract(off)
  __shared__ float At[DE * 128];  // 32 KB
  __shared__ float Bt[DE * 128];  // 32 KB
  int t = threadIdx.x;
  int tx = t & 15, ty = t >> 4;
  int ty8 = ty * 8, tx8 = tx * 8;
  int bid = (int)blockIdx.x;
  int rows0 = (bid >> 2) * 128;  // global row base (128 | 4096: single batch)
  int colseg = bid & 3;
  int b = rows0 >> 12;
  int colbase = colseg * 1024;  // within batch

  {  // stage At (once): thread -> row t>>1, d-half (t&1)*32
    int r = t >> 1, d0 = (t & 1) * 32;
    const float* src = xe + (size_t)(rows0 + r) * DE + d0;
#pragma unroll
    for (int j = 0; j < 8; ++j) {
      float4 v = ((const float4*)src)[j];
      int d = d0 + 4 * j;
      At[(d + 0) * 128 + r] = v.x;
      At[(d + 1) * 128 + r] = v.y;
      At[(d + 2) * 128 + r] = v.z;
      At[(d + 3) * 128 + r] = v.w;
    }
  }

  double tc = (double)temp[0];
  float s32 = (float)exp(fmin(fmax(tc, -5.0), 5.0));

  float sqr[8];
  {
    float4 v0 = *(const float4*)&sq[rows0 + ty8];
    float4 v1 = *(const float4*)&sq[rows0 + ty8 + 4];
    sqr[0] = v0.x; sqr[1] = v0.y; sqr[2] = v0.z; sqr[3] = v0.w;
    sqr[4] = v1.x; sqr[5] = v1.y; sqr[6] = v1.z; sqr[7] = v1.w;
  }
  float thrv[8];
  if (PASSB) {
#pragma unroll
    for (int r = 0; r < 8; ++r) thrv[r] = thrP[rows0 + ty8 + r] + SCRMARG;
  }
  float mn1[8], mn2[8];
#pragma unroll
  for (int r = 0; r < 8; ++r) { mn1[r] = __builtin_inff(); mn2[r] = __builtin_inff(); }

  for (int tile = 0; tile < 8; ++tile) {
    __syncthreads();  // protect Bt from previous tile's readers
    {                 // stage Bt
      int c = t >> 1, d0 = (t & 1) * 32;
      const float* src =
          xe + (size_t)((b << 12) + colbase + tile * 128 + c) * DE + d0;
#pragma unroll
      for (int j = 0; j < 8; ++j) {
        float4 v = ((const float4*)src)[j];
        int d = d0 + 4 * j;
        Bt[(d + 0) * 128 + c] = v.x;
        Bt[(d + 1) * 128 + c] = v.y;
        Bt[(d + 2) * 128 + c] = v.z;
        Bt[(d + 3) * 128 + c] = v.w;
      }
    }
    __syncthreads();

    float acc[8][8];
#pragma unroll
    for (int r = 0; r < 8; ++r)
#pragma unroll
      for (int c = 0; c < 8; ++c) acc[r][c] = 0.f;

#pragma unroll 4
    for (int d = 0; d < DE; ++d) {  // d ascending: golden seq-FMA order per (r,c)
      float4 a0 = *(const float4*)&At[d * 128 + ty8];
      float4 a1 = *(const float4*)&At[d * 128 + ty8 + 4];
      float4 b0 = *(const float4*)&Bt[d * 128 + tx8];
      float4 b1 = *(const float4*)&Bt[d * 128 + tx8 + 4];
      float Ar[8] = {a0.x, a0.y, a0.z, a0.w, a1.x, a1.y, a1.z, a1.w};
      float Bc[8] = {b0.x, b0.y, b0.z, b0.w, b1.x, b1.y, b1.z, b1.w};
#pragma unroll
      for (int r = 0; r < 8; ++r)
#pragma unroll
        for (int c = 0; c < 8; ++c)
          acc[r][c] = __builtin_fmaf(Ar[r], Bc[c], acc[r][c]);
    }

    float sqc[8];
    {
      const float* sb = sq + (b << 12) + colbase + tile * 128 + tx8;
      float4 v0 = *(const float4*)&sb[0];
      float4 v1 = *(const float4*)&sb[4];
      sqc[0] = v0.x; sqc[1] = v0.y; sqc[2] = v0.z; sqc[3] = v0.w;
      sqc[4] = v1.x; sqc[5] = v1.y; sqc[6] = v1.z; sqc[7] = v1.w;
    }
#pragma unroll
    for (int r = 0; r < 8; ++r) {
#pragma unroll
      for (int c = 0; c < 8; ++c) {
        float u = (sqr[r] + sqc[c]) - 2.0f * acc[r][c];
        float P = fmaxf(u, 0.0f) * s32;  // bitwise = r7 chain
        if (PASSB) {
          if ((P - GMAXF) < thrv[r]) {  // sound screen
            int row = rows0 + ty8 + r;
            int colAbs = colbase + tile * 128 + tx8 + c;
            int idx = atomicAdd(&cnt[row], 1);
            if (idx < CAP)
              cand[(size_t)row * CAP + idx] =
                  make_uint2(__float_as_uint(P), (unsigned)colAbs);
          }
        } else {
          if (P < mn2[r]) {
            if (P < mn1[r]) { mn2[r] = mn1[r]; mn1[r] = P; }
            else mn2[r] = P;
          }
        }
      }
    }
  }

  if (!PASSB) {
#pragma unroll
    for (int r = 0; r < 8; ++r)
      cellmin[(size_t)(rows0 + ty8 + r) * 64 + colseg * 16 + tx] =
          make_float2(mn1[r], mn2[r]);
  }
}

// ---------------- K4: thrP[row] = 16th-smallest of cellmin union + pad ----------------
__global__ __launch_bounds__(256) void thr_kernel(
    const float2* __restrict__ cellmin, float* __restrict__ thrP,
    int* __restrict__ cnt) {
  int row = (int)blockIdx.x * 256 + (int)threadIdx.x;
  const float2* cm = cellmin + (size_t)row * 64;
  float tv[16];
#pragma unroll
  for (int k = 0; k < 16; ++k) tv[k] = __builtin_inff();
  for (int i = 0; i < 64; ++i) {
    float2 v2 = cm[i];
#pragma unroll
    for (int j = 0; j < 2; ++j) {
      float v = j ? v2.y : v2.x;
      if (v < tv[15]) {
#pragma unroll
        for (int k = 15; k >= 1; --k) {
          bool ltk = v < tv[k], ltk1 = v < tv[k - 1];
          tv[k] = ltk ? (ltk1 ? tv[k - 1] : v) : tv[k];
        }
        if (v < tv[0]) tv[0] = v;
      }
    }
  }
  thrP[row] = tv[15] + GMINPAD;  // >= true 16th-smallest lq (provable)
  cnt[row] = 0;
}

// ---------------- K6: exact lq on candidates, full (lq,col) sort -> outputs ----------------
__global__ __launch_bounds__(256) void select_kernel(
    const uint2* __restrict__ cand, const int* __restrict__ cnt,
    const float* __restrict__ q, float* __restrict__ e0,
    float* __restrict__ e1, float* __restrict__ lp) {
#pragma clang fp contract(off)
  int row = (int)blockIdx.x * 256 + (int)threadIdx.x;
  int b = row >> 12, n = row & (NN - 1);
  int c = cnt[row];
  if (c > CAP) c = CAP;
  const uint2* cb = cand + (size_t)row * CAP;
  const float* qrow = q + ((size_t)b * NN + n) * NN;
  float tv[16];
  int ti[16];
#pragma unroll
  for (int k = 0; k < 16; ++k) { tv[k] = __builtin_inff(); ti[k] = 0x7FFFFFFF; }
  for (int i = 0; i < c; ++i) {
    uint2 e = cb[i];
    float P = __uint_as_float(e.x);
    int col = (int)e.y;
    float qv = qrow[col];
    float t1 = qv + 1e-8f;
    float l1 = (float)log((double)t1);  // correctly-rounded f32 log (r7-verified)
    float G = (float)log((double)(-l1));
    float lq = P - G;
    // sort by (lq, col): deterministic regardless of append order; jax-stable ties
    bool lt15 = (lq < tv[15]) || (lq == tv[15] && col < ti[15]);
    if (lt15) {
#pragma unroll
      for (int k = 15; k >= 1; --k) {
        bool ltk = (lq < tv[k]) || (lq == tv[k] && col < ti[k]);
        bool ltk1 = (lq < tv[k - 1]) || (lq == tv[k - 1] && col < ti[k - 1]);
        tv[k] = ltk ? (ltk1 ? tv[k - 1] : lq) : tv[k];
        ti[k] = ltk ? (ltk1 ? ti[k - 1] : col) : ti[k];
      }
      bool lt0 = (lq < tv[0]) || (lq == tv[0] && col < ti[0]);
      if (lt0) { tv[0] = lq; ti[0] = col; }
    }
  }
  size_t o = (size_t)row * KK;
#pragma unroll
  for (int k = 0; k < KK; ++k) {
    lp[o + k] = -tv[k];
    e0[o + k] = (float)(ti[k] + b * NN);
    e1[o + k] = (float)(n + b * NN);
  }
}

extern "C" void kernel_launch(void* const* d_in, const int* in_sizes, int n_in,
                              void* d_out, int out_size, void* d_ws,
                              size_t ws_size, hipStream_t stream) {
  (void)in_sizes; (void)n_in; (void)out_size; (void)ws_size;
  const float* x = (const float*)d_in[0];
  // d_in[1] = A (unused placeholder)
  const float* W = (const float*)d_in[2];
  const float* bias = (const float*)d_in[3];
  const float* temp = (const float*)d_in[4];
  const float* q = (const float*)d_in[5];

  float* xe = (float*)d_out;                 // [4,4096,64]
  float* e0 = xe + (size_t)BATCH * NN * DE;  // edges row 0 (indices)
  float* e1 = e0 + (size_t)BATCH * NN * KK;  // edges row 1 (rows)
  float* lp = e1 + (size_t)BATCH * NN * KK;  // logprobs

  const int ROWS = BATCH * NN;  // 16384
  char* ws = (char*)d_ws;
  float* sq = (float*)ws;                          // 64 KB
  float* thrP = (float*)(ws + (64 << 10));         // 64 KB
  int* cnt = (int*)(ws + (128 << 10));             // 64 KB
  float2* cellmin = (float2*)(ws + (192 << 10));   // 16384*64*8 = 8 MB
  uint2* cand = (uint2*)(ws + (192 << 10) + (size_t)ROWS * 64 * 8);  // 16 MB
  // total ~24.4 MB; ws_size >= 25.2 MB proven by r11's SEGS=16 selection

  embed_kernel<<<BATCH * NN / 4, 256, 0, stream>>>(x, W, bias, xe);
  sqnorm_kernel<<<ROWS / 256, 256, 0, stream>>>(xe, sq);
  gemm_pass_kernel<false><<<(ROWS / 128) * 4, 256, 0, stream>>>(
      xe, sq, temp, cellmin, thrP, cnt, cand);
  thr_kernel<<<ROWS / 256, 256, 0, stream>>>(cellmin, thrP, cnt);
  gemm_pass_kernel<true><<<(ROWS / 128) * 4, 256, 0, stream>>>(
      xe, sq, temp, cellmin, thrP, cnt, cand);
  select_kernel<<<ROWS / 256, 256, 0, stream>>>(cand, cnt, q, e0, e1, lp);
}